// Round 3
// baseline (4984.947 us; speedup 1.0000x reference)
//
#include <hip/hip_runtime.h>

// GNN (T-GCN style) on MI355X — fp32 round 1 (resubmit #2; rounds 1-2 hit broker timeouts).
// Reassociated: per step
//   P = A@x (12 cols) ; h0 = lrelu(P@W0+b0)
//   Q = A@h0 (128)    ; h1 = lrelu(Q@W1+b1)
//   R = A@h1 (128)    ; AT = [P|Q|R] (N x 268, written in place)
//   s = lrelu(AT@W2+b2) @ W3   (fused, xt never materialized)
//   yp = A@s + b3 ; out[:,t] = yp ; x = [x[:,1:], yp]

constexpr int TP  = 12;    // T_PAST
constexpr int HID = 128;   // HIDDEN
constexpr int TMP = 268;   // TEMP
constexpr int TF  = 12;    // T_FUTURE

__device__ __forceinline__ float lrelu(float v){ return v >= 0.0f ? v : 0.01f*v; }

// ---------------- preprocessing ----------------

__global__ void k_init(float* __restrict__ deg, int* __restrict__ cnt, int n){
  int i = blockIdx.x*256 + threadIdx.x;
  if (i < n){ deg[i] = 0.0f; cnt[i] = 0; }
}

__global__ void k_degcnt(const int* __restrict__ ei, const float* __restrict__ ew,
                         float* __restrict__ deg, int* __restrict__ cnt, int E){
  int e = blockIdx.x*256 + threadIdx.x;
  if (e < E){
    int d = ei[E + e];             // edge_index[1][e] (dst)
    atomicAdd(&deg[d], ew[e]);
    atomicAdd(&cnt[d], 1);
  }
}

__global__ void k_dinv(float* __restrict__ deg, int n){
  int i = blockIdx.x*256 + threadIdx.x;
  if (i < n) deg[i] = 1.0f / sqrtf(deg[i] + 1.0f);   // self-loop weight 1 included
}

__global__ __launch_bounds__(1024)
void k_scan1(const int* __restrict__ cnt, int* __restrict__ rowptr,
             int* __restrict__ bsum, int n){
  __shared__ int wtot[16];
  int tid = threadIdx.x;
  int i = blockIdx.x*1024 + tid;
  int v = (i < n) ? cnt[i] : 0;
  #pragma unroll
  for (int off = 1; off < 64; off <<= 1){
    int t = __shfl_up(v, off, 64);
    if ((tid & 63) >= off) v += t;
  }
  int wid = tid >> 6;
  if ((tid & 63) == 63) wtot[wid] = v;
  __syncthreads();
  if (tid < 16){
    int t = wtot[tid];
    #pragma unroll
    for (int off = 1; off < 16; off <<= 1){
      int u = __shfl_up(t, off, 64);
      if (tid >= off) t += u;
    }
    wtot[tid] = t;
  }
  __syncthreads();
  int base = (wid > 0) ? wtot[wid-1] : 0;
  int incl = v + base;
  if (i < n) rowptr[i+1] = incl;       // block-local inclusive scan
  if (tid == 1023) bsum[blockIdx.x] = incl;
}

__global__ void k_scan2(int* __restrict__ bsum, int nb){
  if (blockIdx.x == 0 && threadIdx.x == 0){
    int run = 0;
    for (int j = 0; j < nb; ++j){ int t = bsum[j]; bsum[j] = run; run += t; }
  }
}

__global__ void k_scan3(const int* __restrict__ cnt, int* __restrict__ rowptr,
                        int* __restrict__ cursor, const int* __restrict__ bsum, int n){
  int i = blockIdx.x*256 + threadIdx.x;
  if (i < n){
    int f = rowptr[i+1] + bsum[i >> 10];
    rowptr[i+1] = f;
    cursor[i] = f - cnt[i];            // = rowptr[i]
    if (i == 0) rowptr[0] = 0;
  }
}

__global__ void k_scatter(const int* __restrict__ ei, const float* __restrict__ ew,
                          const float* __restrict__ dinv, int* __restrict__ cursor,
                          int* __restrict__ csr_src, float* __restrict__ csr_w, int E){
  int e = blockIdx.x*256 + threadIdx.x;
  if (e < E){
    int s = ei[e], d = ei[E + e];
    int p = atomicAdd(&cursor[d], 1);
    csr_src[p] = s;
    csr_w[p] = dinv[s] * ew[e] * dinv[d];
  }
}

__global__ void k_copyx(const float* __restrict__ xin, float* __restrict__ x, int total){
  int i = blockIdx.x*256 + threadIdx.x;
  if (i < total) x[i] = xin[i];
}

// ---------------- per-step kernels ----------------

// P = A@x -> AT cols [0,12).  One node per wave; 16-lane feature group x 4-way edge split.
__global__ __launch_bounds__(256)
void k_spmm12(const float* __restrict__ x, const int* __restrict__ rowptr,
              const int* __restrict__ csr_src, const float* __restrict__ csr_w,
              const float* __restrict__ dinv, float* __restrict__ AT, int n){
  int lane = threadIdx.x & 63;
  int wid  = __builtin_amdgcn_readfirstlane(threadIdx.x >> 6);
  int node = blockIdx.x*4 + wid;
  if (node >= n) return;
  int f = lane & 15;
  int sub = lane >> 4;
  int k0 = rowptr[node], k1 = rowptr[node+1];
  float acc = 0.0f;
  if (sub == 0 && f < TP){
    float di = dinv[node];
    acc = di*di*x[node*TP + f];
  }
  for (int k = k0 + sub; k < k1; k += 4){
    float w = csr_w[k];
    int s = csr_src[k];
    if (f < TP) acc += w * x[s*TP + f];
  }
  acc += __shfl_xor(acc, 16, 64);
  acc += __shfl_xor(acc, 32, 64);
  if (sub == 0 && f < TP) AT[(long)node*TMP + f] = acc;
}

// h0 = lrelu(P @ W0 + b0) ; P = AT cols [0,12)
__global__ __launch_bounds__(256)
void k_mm0(const float* __restrict__ AT, const float* __restrict__ W0,
           const float* __restrict__ b0, float* __restrict__ h0, int n){
  __shared__ float Ws[TP*HID];
  for (int j = threadIdx.x; j < TP*HID; j += 256) Ws[j] = W0[j];
  __syncthreads();
  int f = threadIdx.x & 127;
  int half = threadIdx.x >> 7;
  float bf = b0[f];
  int base = blockIdx.x * 8;
  #pragma unroll
  for (int r = 0; r < 4; ++r){
    int node = base + half*4 + r;
    if (node < n){
      const float* arow = AT + (long)node*TMP;
      float acc = bf;
      #pragma unroll
      for (int k = 0; k < TP; ++k) acc += arow[k]*Ws[k*HID + f];
      h0[(long)node*HID + f] = lrelu(acc);
    }
  }
}

// out(AT cols [colofs, colofs+128)) = A @ h.  One node per wave, float2 per lane.
__global__ __launch_bounds__(256)
void k_spmm128(const float* __restrict__ h, const int* __restrict__ rowptr,
               const int* __restrict__ csr_src, const float* __restrict__ csr_w,
               const float* __restrict__ dinv, float* __restrict__ AT, int colofs, int n){
  int lane = threadIdx.x & 63;
  int wid  = __builtin_amdgcn_readfirstlane(threadIdx.x >> 6);
  int node = blockIdx.x*4 + wid;
  if (node >= n) return;
  int k0 = rowptr[node], k1 = rowptr[node+1];
  float di = dinv[node];
  float2 acc = *(const float2*)(h + (long)node*HID + 2*lane);
  acc.x *= di*di; acc.y *= di*di;
  for (int k = k0; k < k1; ++k){
    float w = csr_w[k];          // wave-uniform -> scalar loads
    int s = csr_src[k];
    float2 v = *(const float2*)(h + (long)s*HID + 2*lane);
    acc.x += w*v.x; acc.y += w*v.y;
  }
  float* orow = AT + (long)node*TMP + colofs;
  orow[2*lane]   = acc.x;
  orow[2*lane+1] = acc.y;
}

// Generic tiled fp32 matmul: C = lrelu(A[M,K] @ W[K,Ncols] + bias).
// FUSE3: instead of storing C, also multiply by W3[Ncols] and reduce to sout[M].
// 256 threads, 64x64 tile, 4x4 per thread, BK=16.
template<bool FUSE3>
__global__ __launch_bounds__(256)
void k_mm(const float* __restrict__ A, int lda,
          const float* __restrict__ W, int ldw,
          const float* __restrict__ bias,
          float* __restrict__ C, int ldc,
          const float* __restrict__ W3, float* __restrict__ sout,
          int M, int K, int Ncols){
  __shared__ float As[16][68];   // [k][m], padded
  __shared__ float Ws[16][64];   // [k][n]
  int tid = threadIdx.x;
  int tx = tid & 15, ty = tid >> 4;
  int m0 = blockIdx.x * 64;
  int nTiles = (Ncols + 63) >> 6;
  float sacc[4] = {0.f,0.f,0.f,0.f};
  int ntBeg = FUSE3 ? 0 : blockIdx.y;
  int ntEnd = FUSE3 ? nTiles : (int)blockIdx.y + 1;
  for (int nt = ntBeg; nt < ntEnd; ++nt){
    int n0 = nt * 64;
    float acc[4][4];
    #pragma unroll
    for (int i = 0; i < 4; ++i)
      #pragma unroll
      for (int j = 0; j < 4; ++j) acc[i][j] = 0.f;

    for (int k0 = 0; k0 < K; k0 += 16){
      // stage A tile (transposed)
      {
        int rr = tid >> 2;
        int kb = (tid & 3) * 4;
        int row = m0 + rr;
        float4 v = {0.f,0.f,0.f,0.f};
        int k = k0 + kb;
        if (row < M){
          if (k + 3 < K){
            v = *(const float4*)(A + (long)row*lda + k);
          } else {
            v.x = (k   < K) ? A[(long)row*lda + k  ] : 0.f;
            v.y = (k+1 < K) ? A[(long)row*lda + k+1] : 0.f;
            v.z = (k+2 < K) ? A[(long)row*lda + k+2] : 0.f;
            v.w = 0.f;
          }
        }
        As[kb+0][rr] = v.x; As[kb+1][rr] = v.y; As[kb+2][rr] = v.z; As[kb+3][rr] = v.w;
      }
      // stage W tile
      {
        int kk = tid >> 4;
        int c0 = (tid & 15) * 4;
        int k = k0 + kk;
        int col = n0 + c0;
        float4 v = {0.f,0.f,0.f,0.f};
        if (k < K){
          if (col + 3 < Ncols){
            v = *(const float4*)(W + (long)k*ldw + col);
          } else {
            if (col   < Ncols) v.x = W[(long)k*ldw + col  ];
            if (col+1 < Ncols) v.y = W[(long)k*ldw + col+1];
            if (col+2 < Ncols) v.z = W[(long)k*ldw + col+2];
          }
        }
        *(float4*)&Ws[kk][c0] = v;
      }
      __syncthreads();
      #pragma unroll
      for (int kk = 0; kk < 16; ++kk){
        float4 a4 = *(const float4*)&As[kk][ty*4];
        float4 w4 = *(const float4*)&Ws[kk][tx*4];
        float av[4] = {a4.x, a4.y, a4.z, a4.w};
        float wv[4] = {w4.x, w4.y, w4.z, w4.w};
        #pragma unroll
        for (int i = 0; i < 4; ++i)
          #pragma unroll
          for (int j = 0; j < 4; ++j) acc[i][j] += av[i]*wv[j];
      }
      __syncthreads();
    }
    // epilogue
    if (!FUSE3){
      #pragma unroll
      for (int i = 0; i < 4; ++i){
        int row = m0 + ty*4 + i;
        if (row < M){
          #pragma unroll
          for (int j = 0; j < 4; ++j){
            int col = n0 + tx*4 + j;
            if (col < Ncols){
              float v = lrelu(acc[i][j] + bias[col]);
              C[(long)row*ldc + col] = v;
            }
          }
        }
      }
    } else {
      #pragma unroll
      for (int i = 0; i < 4; ++i){
        #pragma unroll
        for (int j = 0; j < 4; ++j){
          int col = n0 + tx*4 + j;
          if (col < Ncols){
            float v = lrelu(acc[i][j] + bias[col]);
            sacc[i] += v * W3[col];
          }
        }
      }
    }
  }
  if (FUSE3){
    #pragma unroll
    for (int i = 0; i < 4; ++i){
      float v = sacc[i];
      v += __shfl_xor(v, 1, 64);
      v += __shfl_xor(v, 2, 64);
      v += __shfl_xor(v, 4, 64);
      v += __shfl_xor(v, 8, 64);
      sacc[i] = v;
    }
    if (tx == 0){
      #pragma unroll
      for (int i = 0; i < 4; ++i){
        int row = m0 + ty*4 + i;
        if (row < M) sout[row] = sacc[i];
      }
    }
  }
}

// yp = A@s + b3 ; out[:,t] = yp ; x = [x[:,1:], yp]
__global__ void k_finalize(const float* __restrict__ s, const int* __restrict__ rowptr,
                           const int* __restrict__ csr_src, const float* __restrict__ csr_w,
                           const float* __restrict__ dinv, const float* __restrict__ b3,
                           float* __restrict__ x, float* __restrict__ out, int t, int n){
  int i = blockIdx.x*256 + threadIdx.x;
  if (i >= n) return;
  float di = dinv[i];
  float acc = di*di*s[i];
  int k1 = rowptr[i+1];
  for (int k = rowptr[i]; k < k1; ++k) acc += csr_w[k]*s[csr_src[k]];
  float yp = acc + b3[0];
  out[(long)i*TF + t] = yp;
  float xr[TP];
  #pragma unroll
  for (int j = 0; j < TP; ++j) xr[j] = x[(long)i*TP + j];
  #pragma unroll
  for (int j = 0; j < TP-1; ++j) x[(long)i*TP + j] = xr[j+1];
  x[(long)i*TP + TP-1] = yp;
}

// ---------------- launcher ----------------

extern "C" void kernel_launch(void* const* d_in, const int* in_sizes, int n_in,
                              void* d_out, int out_size, void* d_ws, size_t ws_size,
                              hipStream_t stream){
  const float* xin = (const float*)d_in[0];
  const int*   ei  = (const int*)  d_in[1];
  const float* ew  = (const float*)d_in[2];
  const float* W0  = (const float*)d_in[3];
  const float* b0  = (const float*)d_in[4];
  const float* W1  = (const float*)d_in[5];
  const float* b1  = (const float*)d_in[6];
  const float* W2  = (const float*)d_in[7];
  const float* b2  = (const float*)d_in[8];
  const float* W3  = (const float*)d_in[9];
  const float* b3  = (const float*)d_in[10];
  float* out = (float*)d_out;

  int n = in_sizes[0] / TP;
  int E = in_sizes[2];

  // workspace carve (all 256B aligned)
  char* p = (char*)d_ws;
  auto carve = [&](size_t bytes) -> void* {
    void* r = (void*)p;
    p += (bytes + 255) & ~(size_t)255;
    return r;
  };
  float* dinv    = (float*)carve((size_t)n*4);
  int*   cnt     = (int*)  carve((size_t)n*4);
  int*   rowptr  = (int*)  carve((size_t)(n+1)*4);
  int*   cursor  = (int*)  carve((size_t)n*4);
  int*   bsum    = (int*)  carve(1024*4);
  int*   csr_src = (int*)  carve((size_t)E*4);
  float* csr_w   = (float*)carve((size_t)E*4);
  float* x       = (float*)carve((size_t)n*TP*4);
  float* h0      = (float*)carve((size_t)n*HID*4);   // holds h0, then h1
  float* AT      = (float*)carve((size_t)n*TMP*4);   // [P | Q | R]
  float* sbuf    = (float*)carve((size_t)n*4);

  int gN   = (n + 255) / 256;
  int gE   = (E + 255) / 256;
  int nb   = (n + 1023) / 1024;
  int gW4  = (n + 3) / 4;          // wave-per-node kernels
  int gMM  = (n + 63) / 64;        // matmul row tiles

  k_init   <<<gN, 256, 0, stream>>>(dinv, cnt, n);
  k_degcnt <<<gE, 256, 0, stream>>>(ei, ew, dinv, cnt, E);
  k_dinv   <<<gN, 256, 0, stream>>>(dinv, n);
  k_scan1  <<<nb, 1024, 0, stream>>>(cnt, rowptr, bsum, n);
  k_scan2  <<<1, 64, 0, stream>>>(bsum, nb);
  k_scan3  <<<gN, 256, 0, stream>>>(cnt, rowptr, cursor, bsum, n);
  k_scatter<<<gE, 256, 0, stream>>>(ei, ew, dinv, cursor, csr_src, csr_w, E);
  k_copyx  <<<(n*TP + 255)/256, 256, 0, stream>>>(xin, x, n*TP);

  for (int t = 0; t < TF; ++t){
    // P = A@x
    k_spmm12<<<gW4, 256, 0, stream>>>(x, rowptr, csr_src, csr_w, dinv, AT, n);
    // h0 = lrelu(P@W0+b0)
    k_mm0<<<(n + 7)/8, 256, 0, stream>>>(AT, W0, b0, h0, n);
    // Q = A@h0 -> AT cols 12..139
    k_spmm128<<<gW4, 256, 0, stream>>>(h0, rowptr, csr_src, csr_w, dinv, AT, TP, n);
    // h1 = lrelu(Q@W1+b1) -> reuse h0 buffer
    k_mm<false><<<dim3(gMM, 2), 256, 0, stream>>>(AT + TP, TMP, W1, HID, b1,
                                                  h0, HID, nullptr, nullptr,
                                                  n, HID, HID);
    // R = A@h1 -> AT cols 140..267
    k_spmm128<<<gW4, 256, 0, stream>>>(h0, rowptr, csr_src, csr_w, dinv, AT, TP + HID, n);
    // s = lrelu(AT@W2+b2) @ W3   (xt never stored)
    k_mm<true><<<dim3(gMM, 1), 256, 0, stream>>>(AT, TMP, W2, TMP, b2,
                                                 nullptr, 0, W3, sbuf,
                                                 n, TMP, TMP);
    // yp = A@s + b3 ; out ; shift x
    k_finalize<<<gN, 256, 0, stream>>>(sbuf, rowptr, csr_src, csr_w, dinv, b3,
                                       x, out, t, n);
  }
}

// Round 5
// 3921.426 us; speedup vs baseline: 1.2712x; 1.2712x over previous
//
#include <hip/hip_runtime.h>

// GNN (T-GCN style) on MI355X — round 4 resubmit (broker timeout; never ran).
// MFMA bf16 hi/lo split for dense matmuls.
// Per step:
//   P = A@x (12 cols, ->AT cols 0..11, hi/lo bf16) ; h0 = lrelu(P@W0+b0)  [fp32 small]
//   Q = A@h0 -> AT cols 16..143 (hi/lo)
//   h1 = lrelu(Q@W1+b1)   [MFMA split-bf16]
//   R = A@h1 -> AT cols 144..271 (hi/lo)
//   s = lrelu(AT@W2+b2)@W3   [MFMA split-bf16, FUSE3, xt never stored]
//   yp = A@s + b3 ; out[:,t] ; x shift
// AT k-layout: [x(12) | zero(4) | h0(128) | h1(128) | zero(16)] = 288 = 9*32.
// W2 rows permuted to match: orig = k' (k'<12), k'-4 (16<=k'<272), else zero.

constexpr int TP   = 12;
constexpr int HID  = 128;
constexpr int TF   = 12;
constexpr int KPAD = 288;   // 9 * 32
constexpr int NCOL2 = 272;  // 17 * 16 output cols for W2 matmul (268 real + 4 pad)

typedef __attribute__((ext_vector_type(8))) __bf16 b8v;   // 8 bf16 = 4 VGPR
typedef __attribute__((ext_vector_type(4))) float  f4v;   // MFMA accumulator

__device__ __forceinline__ f4v mfma16(b8v a, b8v b, f4v c){
  return __builtin_amdgcn_mfma_f32_16x16x32_bf16(a, b, c, 0, 0, 0);
}

__device__ __forceinline__ float lrelu(float v){ return v >= 0.0f ? v : 0.01f*v; }

__device__ __forceinline__ unsigned short bfu(__bf16 h){
  return __builtin_bit_cast(unsigned short, h);
}

// ---------------- preprocessing ----------------

__global__ void k_init(float* __restrict__ deg, int* __restrict__ cnt, int n){
  int i = blockIdx.x*256 + threadIdx.x;
  if (i < n){ deg[i] = 0.0f; cnt[i] = 0; }
}

__global__ void k_degcnt(const int* __restrict__ ei, const float* __restrict__ ew,
                         float* __restrict__ deg, int* __restrict__ cnt, int E){
  int e = blockIdx.x*256 + threadIdx.x;
  if (e < E){
    int d = ei[E + e];
    atomicAdd(&deg[d], ew[e]);
    atomicAdd(&cnt[d], 1);
  }
}

__global__ void k_dinv(float* __restrict__ deg, int n){
  int i = blockIdx.x*256 + threadIdx.x;
  if (i < n) deg[i] = 1.0f / sqrtf(deg[i] + 1.0f);
}

__global__ __launch_bounds__(1024)
void k_scan1(const int* __restrict__ cnt, int* __restrict__ rowptr,
             int* __restrict__ bsum, int n){
  __shared__ int wtot[16];
  int tid = threadIdx.x;
  int i = blockIdx.x*1024 + tid;
  int v = (i < n) ? cnt[i] : 0;
  #pragma unroll
  for (int off = 1; off < 64; off <<= 1){
    int t = __shfl_up(v, off, 64);
    if ((tid & 63) >= off) v += t;
  }
  int wid = tid >> 6;
  if ((tid & 63) == 63) wtot[wid] = v;
  __syncthreads();
  if (tid < 16){
    int t = wtot[tid];
    #pragma unroll
    for (int off = 1; off < 16; off <<= 1){
      int u = __shfl_up(t, off, 64);
      if (tid >= off) t += u;
    }
    wtot[tid] = t;
  }
  __syncthreads();
  int base = (wid > 0) ? wtot[wid-1] : 0;
  int incl = v + base;
  if (i < n) rowptr[i+1] = incl;
  if (tid == 1023) bsum[blockIdx.x] = incl;
}

__global__ void k_scan2(int* __restrict__ bsum, int nb){
  if (blockIdx.x == 0 && threadIdx.x == 0){
    int run = 0;
    for (int j = 0; j < nb; ++j){ int t = bsum[j]; bsum[j] = run; run += t; }
  }
}

__global__ void k_scan3(const int* __restrict__ cnt, int* __restrict__ rowptr,
                        int* __restrict__ cursor, const int* __restrict__ bsum, int n){
  int i = blockIdx.x*256 + threadIdx.x;
  if (i < n){
    int f = rowptr[i+1] + bsum[i >> 10];
    rowptr[i+1] = f;
    cursor[i] = f - cnt[i];
    if (i == 0) rowptr[0] = 0;
  }
}

__global__ void k_scatter(const int* __restrict__ ei, const float* __restrict__ ew,
                          const float* __restrict__ dinv, int* __restrict__ cursor,
                          int* __restrict__ csr_src, float* __restrict__ csr_w, int E){
  int e = blockIdx.x*256 + threadIdx.x;
  if (e < E){
    int s = ei[e], d = ei[E + e];
    int p = atomicAdd(&cursor[d], 1);
    csr_src[p] = s;
    csr_w[p] = dinv[s] * ew[e] * dinv[d];
  }
}

__global__ void k_copyx(const float* __restrict__ xin, float* __restrict__ x, int total){
  int i = blockIdx.x*256 + threadIdx.x;
  if (i < total) x[i] = xin[i];
}

// Build W2^T padded+permuted hi/lo planes [NCOL2][KPAD]; also padded b2 / W3.
__global__ void k_convW2(const float* __restrict__ W2, const float* __restrict__ b2,
                         const float* __restrict__ W3,
                         __bf16* __restrict__ W2Th, __bf16* __restrict__ W2Tl,
                         float* __restrict__ b2p, float* __restrict__ W3p){
  int idx = blockIdx.x*256 + threadIdx.x;
  if (idx >= NCOL2*KPAD) return;
  int nn = idx / KPAD, kk = idx - nn*KPAD;
  int r = (kk < 12) ? kk : ((kk < 16) ? -1 : ((kk < 272) ? kk - 4 : -1));
  float v = (r >= 0 && nn < 268) ? W2[r*268 + nn] : 0.0f;
  __bf16 hb = (__bf16)v;
  long o = (long)nn*KPAD + kk;
  W2Th[o] = hb;
  W2Tl[o] = (__bf16)(v - (float)hb);
  if (kk == 0){
    b2p[nn] = (nn < 268) ? b2[nn] : 0.0f;
    W3p[nn] = (nn < 268) ? W3[nn] : 0.0f;
  }
}

// W1^T hi/lo planes [128][128].
__global__ void k_convW1(const float* __restrict__ W1,
                         __bf16* __restrict__ W1Th, __bf16* __restrict__ W1Tl){
  int idx = blockIdx.x*256 + threadIdx.x;
  if (idx >= HID*HID) return;
  int nn = idx >> 7, kk = idx & 127;
  float v = W1[kk*HID + nn];
  __bf16 hb = (__bf16)v;
  W1Th[idx] = hb;
  W1Tl[idx] = (__bf16)(v - (float)hb);
}

// Zero AT pad cols 272..287 (once per launch; ws is re-poisoned each call).
__global__ void k_zerotail(__bf16* __restrict__ ATh, __bf16* __restrict__ ATl, int npad){
  int i = blockIdx.x*256 + threadIdx.x;
  if (i >= npad*16) return;
  int row = i >> 4, c = 272 + (i & 15);
  long o = (long)row*KPAD + c;
  ATh[o] = (__bf16)0.0f;
  ATl[o] = (__bf16)0.0f;
}

// ---------------- per-step kernels ----------------

// P = A@x -> AT cols 0..11 (hi/lo), cols 12..15 zeroed.  One node per wave.
__global__ __launch_bounds__(256)
void k_spmm12(const float* __restrict__ x, const int* __restrict__ rowptr,
              const int* __restrict__ csr_src, const float* __restrict__ csr_w,
              const float* __restrict__ dinv, __bf16* __restrict__ ATh,
              __bf16* __restrict__ ATl, int n){
  int lane = threadIdx.x & 63;
  int wid  = __builtin_amdgcn_readfirstlane(threadIdx.x >> 6);
  int node = blockIdx.x*4 + wid;
  if (node >= n) return;
  int f = lane & 15;
  int sub = lane >> 4;
  int k0 = rowptr[node], k1 = rowptr[node+1];
  float acc = 0.0f;
  if (sub == 0 && f < TP){
    float di = dinv[node];
    acc = di*di*x[node*TP + f];
  }
  for (int k = k0 + sub; k < k1; k += 4){
    float w = csr_w[k];
    int s = csr_src[k];
    if (f < TP) acc += w * x[s*TP + f];
  }
  acc += __shfl_xor(acc, 16, 64);
  acc += __shfl_xor(acc, 32, 64);
  if (sub == 0){
    long o = (long)node*KPAD + f;
    if (f < TP){
      __bf16 hb = (__bf16)acc;
      ATh[o] = hb;
      ATl[o] = (__bf16)(acc - (float)hb);
    } else {
      ATh[o] = (__bf16)0.0f;
      ATl[o] = (__bf16)0.0f;
    }
  }
}

// h0 = lrelu(P@W0 + b0); P reconstructed hi+lo from AT cols 0..11.
__global__ __launch_bounds__(256)
void k_mm0(const __bf16* __restrict__ ATh, const __bf16* __restrict__ ATl,
           const float* __restrict__ W0, const float* __restrict__ b0,
           float* __restrict__ h0, int n){
  __shared__ float Ws[TP*HID];
  for (int j = threadIdx.x; j < TP*HID; j += 256) Ws[j] = W0[j];
  __syncthreads();
  int f = threadIdx.x & 127;
  int half = threadIdx.x >> 7;
  float bf = b0[f];
  int base = blockIdx.x * 8;
  #pragma unroll
  for (int r = 0; r < 4; ++r){
    int node = base + half*4 + r;
    if (node < n){
      const __bf16* rh = ATh + (long)node*KPAD;
      const __bf16* rl = ATl + (long)node*KPAD;
      float acc = bf;
      #pragma unroll
      for (int k = 0; k < TP; ++k){
        float a = (float)rh[k] + (float)rl[k];
        acc += a * Ws[k*HID + f];
      }
      h0[(long)node*HID + f] = lrelu(acc);
    }
  }
}

// AT cols [colofs, colofs+128) = A@h (hi/lo bf16). One node per wave, float2/lane.
__global__ __launch_bounds__(256)
void k_spmm128(const float* __restrict__ h, const int* __restrict__ rowptr,
               const int* __restrict__ csr_src, const float* __restrict__ csr_w,
               const float* __restrict__ dinv, __bf16* __restrict__ ATh,
               __bf16* __restrict__ ATl, int colofs, int n){
  int lane = threadIdx.x & 63;
  int wid  = __builtin_amdgcn_readfirstlane(threadIdx.x >> 6);
  int node = blockIdx.x*4 + wid;
  if (node >= n) return;
  int k0 = rowptr[node], k1 = rowptr[node+1];
  float di = dinv[node];
  float2 acc = *(const float2*)(h + (long)node*HID + 2*lane);
  acc.x *= di*di; acc.y *= di*di;
  for (int k = k0; k < k1; ++k){
    float w = csr_w[k];          // wave-uniform -> scalar loads
    int s = csr_src[k];
    float2 v = *(const float2*)(h + (long)s*HID + 2*lane);
    acc.x += w*v.x; acc.y += w*v.y;
  }
  long o = (long)node*KPAD + colofs + 2*lane;
  __bf16 hx = (__bf16)acc.x, hy = (__bf16)acc.y;
  __bf16 lx = (__bf16)(acc.x - (float)hx), ly = (__bf16)(acc.y - (float)hy);
  *(unsigned int*)(ATh + o) = ((unsigned int)bfu(hy) << 16) | bfu(hx);
  *(unsigned int*)(ATl + o) = ((unsigned int)bfu(ly) << 16) | bfu(lx);
}

// MFMA split-bf16 matmul. A hi/lo planes [*, lda], B = W^T hi/lo planes [NT*16][ldb].
// Wave w owns rows block*64 + w*16 .. +15; A-frags preloaded once (no re-read).
// acc = Ahi*Bhi + Alo*Bhi + Ahi*Blo (fp32 MFMA accum; dropped lo*lo ~ 2^-18).
// FUSE3: epilogue s[row] = sum_col lrelu(acc+bias[col])*W3[col]; else C=lrelu(acc+bias).
template<int KS, int NT, bool FUSE3>
__global__ __launch_bounds__(256)
void k_mfma(const __bf16* __restrict__ Ah, const __bf16* __restrict__ Al, int lda,
            const __bf16* __restrict__ Bh, const __bf16* __restrict__ Bl, int ldb,
            const float* __restrict__ bias,
            float* __restrict__ C, int ldc,
            const float* __restrict__ W3, float* __restrict__ sout, int M){
  int lane = threadIdx.x & 63;
  int w    = threadIdx.x >> 6;
  int r16  = lane & 15;          // A-frag row / B-frag col / C col
  int kg   = lane >> 4;          // k-group 0..3
  long arow = (long)blockIdx.x*64 + w*16 + r16;
  const __bf16* pAh = Ah + arow*lda + kg*8;
  const __bf16* pAl = Al + arow*lda + kg*8;
  b8v ah[KS], al[KS];
  #pragma unroll
  for (int ks = 0; ks < KS; ++ks){
    ah[ks] = *(const b8v*)(pAh + ks*32);
    al[ks] = *(const b8v*)(pAl + ks*32);
  }
  float sacc[4] = {0.f, 0.f, 0.f, 0.f};
  for (int nt = 0; nt < NT; ++nt){
    const __bf16* pBh = Bh + (long)(nt*16 + r16)*ldb + kg*8;
    const __bf16* pBl = Bl + (long)(nt*16 + r16)*ldb + kg*8;
    f4v acc = {0.f, 0.f, 0.f, 0.f};
    #pragma unroll
    for (int ks = 0; ks < KS; ++ks){
      b8v bh = *(const b8v*)(pBh + ks*32);
      b8v bl = *(const b8v*)(pBl + ks*32);
      acc = mfma16(ah[ks], bh, acc);
      acc = mfma16(al[ks], bh, acc);
      acc = mfma16(ah[ks], bl, acc);
    }
    int col = nt*16 + r16;
    float bb = bias[col];
    if constexpr (FUSE3){
      float w3 = W3[col];
      #pragma unroll
      for (int i = 0; i < 4; ++i) sacc[i] += lrelu(acc[i] + bb) * w3;
    } else {
      #pragma unroll
      for (int i = 0; i < 4; ++i){
        long row = (long)blockIdx.x*64 + w*16 + kg*4 + i;   // C layout: col=lane&15, row=kg*4+i
        if (row < M) C[row*ldc + col] = lrelu(acc[i] + bb);
      }
    }
  }
  if constexpr (FUSE3){
    #pragma unroll
    for (int i = 0; i < 4; ++i){
      float v = sacc[i];
      v += __shfl_xor(v, 1, 64);
      v += __shfl_xor(v, 2, 64);
      v += __shfl_xor(v, 4, 64);
      v += __shfl_xor(v, 8, 64);
      sacc[i] = v;
    }
    if (r16 == 0){
      #pragma unroll
      for (int i = 0; i < 4; ++i){
        long row = (long)blockIdx.x*64 + w*16 + kg*4 + i;
        if (row < M) sout[row] = sacc[i];
      }
    }
  }
}

// yp = A@s + b3 ; out[:,t] = yp ; x = [x[:,1:], yp]
__global__ void k_finalize(const float* __restrict__ s, const int* __restrict__ rowptr,
                           const int* __restrict__ csr_src, const float* __restrict__ csr_w,
                           const float* __restrict__ dinv, const float* __restrict__ b3,
                           float* __restrict__ x, float* __restrict__ out, int t, int n){
  int i = blockIdx.x*256 + threadIdx.x;
  if (i >= n) return;
  float di = dinv[i];
  float acc = di*di*s[i];
  int k1 = rowptr[i+1];
  for (int k = rowptr[i]; k < k1; ++k) acc += csr_w[k]*s[csr_src[k]];
  float yp = acc + b3[0];
  out[(long)i*TF + t] = yp;
  float xr[TP];
  #pragma unroll
  for (int j = 0; j < TP; ++j) xr[j] = x[(long)i*TP + j];
  #pragma unroll
  for (int j = 0; j < TP-1; ++j) x[(long)i*TP + j] = xr[j+1];
  x[(long)i*TP + TP-1] = yp;
}

// ---------------- launcher ----------------

extern "C" void kernel_launch(void* const* d_in, const int* in_sizes, int n_in,
                              void* d_out, int out_size, void* d_ws, size_t ws_size,
                              hipStream_t stream){
  const float* xin = (const float*)d_in[0];
  const int*   ei  = (const int*)  d_in[1];
  const float* ew  = (const float*)d_in[2];
  const float* W0  = (const float*)d_in[3];
  const float* b0  = (const float*)d_in[4];
  const float* W1  = (const float*)d_in[5];
  const float* b1  = (const float*)d_in[6];
  const float* W2  = (const float*)d_in[7];
  const float* b2  = (const float*)d_in[8];
  const float* W3  = (const float*)d_in[9];
  const float* b3  = (const float*)d_in[10];
  float* out = (float*)d_out;

  int n = in_sizes[0] / TP;
  int E = in_sizes[2];
  int npad = ((n + 63) / 64) * 64;

  char* p = (char*)d_ws;
  auto carve = [&](size_t bytes) -> void* {
    void* r = (void*)p;
    p += (bytes + 255) & ~(size_t)255;
    return r;
  };
  float*  dinv    = (float*) carve((size_t)n*4);
  int*    cnt     = (int*)   carve((size_t)n*4);
  int*    rowptr  = (int*)   carve((size_t)(n+1)*4);
  int*    cursor  = (int*)   carve((size_t)n*4);
  int*    bsum    = (int*)   carve(1024*4);
  int*    csr_src = (int*)   carve((size_t)E*4);
  float*  csr_w   = (float*) carve((size_t)E*4);
  float*  x       = (float*) carve((size_t)n*TP*4);
  float*  h       = (float*) carve((size_t)n*HID*4);      // h0 then h1
  __bf16* ATh     = (__bf16*)carve((size_t)npad*KPAD*2);
  __bf16* ATl     = (__bf16*)carve((size_t)npad*KPAD*2);
  __bf16* W2Th    = (__bf16*)carve((size_t)NCOL2*KPAD*2);
  __bf16* W2Tl    = (__bf16*)carve((size_t)NCOL2*KPAD*2);
  __bf16* W1Th    = (__bf16*)carve((size_t)HID*HID*2);
  __bf16* W1Tl    = (__bf16*)carve((size_t)HID*HID*2);
  float*  b2p     = (float*) carve(NCOL2*4);
  float*  W3p     = (float*) carve(NCOL2*4);
  float*  sbuf    = (float*) carve((size_t)n*4);

  int gN  = (n + 255) / 256;
  int gE  = (E + 255) / 256;
  int nb  = (n + 1023) / 1024;
  int gW4 = (n + 3) / 4;
  int gM64 = (n + 63) / 64;

  k_init   <<<gN, 256, 0, stream>>>(dinv, cnt, n);
  k_degcnt <<<gE, 256, 0, stream>>>(ei, ew, dinv, cnt, E);
  k_dinv   <<<gN, 256, 0, stream>>>(dinv, n);
  k_scan1  <<<nb, 1024, 0, stream>>>(cnt, rowptr, bsum, n);
  k_scan2  <<<1, 64, 0, stream>>>(bsum, nb);
  k_scan3  <<<gN, 256, 0, stream>>>(cnt, rowptr, cursor, bsum, n);
  k_scatter<<<gE, 256, 0, stream>>>(ei, ew, dinv, cursor, csr_src, csr_w, E);
  k_copyx  <<<(n*TP + 255)/256, 256, 0, stream>>>(xin, x, n*TP);
  k_convW2 <<<(NCOL2*KPAD + 255)/256, 256, 0, stream>>>(W2, b2, W3, W2Th, W2Tl, b2p, W3p);
  k_convW1 <<<(HID*HID + 255)/256, 256, 0, stream>>>(W1, W1Th, W1Tl);
  k_zerotail<<<(npad*16 + 255)/256, 256, 0, stream>>>(ATh, ATl, npad);

  for (int t = 0; t < TF; ++t){
    k_spmm12<<<gW4, 256, 0, stream>>>(x, rowptr, csr_src, csr_w, dinv, ATh, ATl, n);
    k_mm0<<<(n + 7)/8, 256, 0, stream>>>(ATh, ATl, W0, b0, h, n);
    k_spmm128<<<gW4, 256, 0, stream>>>(h, rowptr, csr_src, csr_w, dinv, ATh, ATl, 16, n);
    // h1 = lrelu(Q@W1+b1): K=128 (4 ksteps), N=128 (8 ntiles)
    k_mfma<4, 8, false><<<gM64, 256, 0, stream>>>(ATh + 16, ATl + 16, KPAD,
                                                  W1Th, W1Tl, HID,
                                                  b1, h, HID, nullptr, nullptr, n);
    k_spmm128<<<gW4, 256, 0, stream>>>(h, rowptr, csr_src, csr_w, dinv, ATh, ATl, 144, n);
    // s = lrelu(AT@W2+b2)@W3: K=288 (9 ksteps), N=272 (17 ntiles), fused
    k_mfma<9, 17, true><<<gM64, 256, 0, stream>>>(ATh, ATl, KPAD,
                                                  W2Th, W2Tl, KPAD,
                                                  b2p, nullptr, 0, W3p, sbuf, n);
    k_finalize<<<gN, 256, 0, stream>>>(sbuf, rowptr, csr_src, csr_w, dinv, b3,
                                       x, out, t, n);
  }
}

// Round 6
// 3632.323 us; speedup vs baseline: 1.3724x; 1.0796x over previous
//
#include <hip/hip_runtime.h>

// GNN (T-GCN style) on MI355X — round 6.
//  * k_mfma: B-fragments batched into register arrays per nt-tile (kills per-k-slice
//    load->wait->mfma serialization seen in r5 counters: MfmaUtil 10%, both pipes idle).
//  * Incremental P: P_new[:,j] = P_old[:,j+1]; only col 11 = A@yp recomputed.
//    k_spmm12 runs once (t=0); k_shiftP handles t>=1. x buffer dropped.
//  * k_spmm128: edge loop unrolled x2 with independent accumulators (2x MLP).
// AT k-layout: [x(12) | zero(4) | h0(128) | h1(128) | zero(16)] = 288 = 9*32.
// W2 rows permuted to match: orig = k' (k'<12), k'-4 (16<=k'<272), else zero.

constexpr int TP   = 12;
constexpr int HID  = 128;
constexpr int TF   = 12;
constexpr int KPAD = 288;   // 9 * 32
constexpr int NCOL2 = 272;  // 17 * 16 output cols for W2 matmul (268 real + 4 pad)

typedef __attribute__((ext_vector_type(8))) __bf16 b8v;   // 8 bf16 = 4 VGPR
typedef __attribute__((ext_vector_type(4))) float  f4v;   // MFMA accumulator

__device__ __forceinline__ f4v mfma16(b8v a, b8v b, f4v c){
  return __builtin_amdgcn_mfma_f32_16x16x32_bf16(a, b, c, 0, 0, 0);
}

__device__ __forceinline__ float lrelu(float v){ return v >= 0.0f ? v : 0.01f*v; }

__device__ __forceinline__ unsigned short bfu(__bf16 h){
  return __builtin_bit_cast(unsigned short, h);
}

// ---------------- preprocessing ----------------

__global__ void k_init(float* __restrict__ deg, int* __restrict__ cnt, int n){
  int i = blockIdx.x*256 + threadIdx.x;
  if (i < n){ deg[i] = 0.0f; cnt[i] = 0; }
}

__global__ void k_degcnt(const int* __restrict__ ei, const float* __restrict__ ew,
                         float* __restrict__ deg, int* __restrict__ cnt, int E){
  int e = blockIdx.x*256 + threadIdx.x;
  if (e < E){
    int d = ei[E + e];
    atomicAdd(&deg[d], ew[e]);
    atomicAdd(&cnt[d], 1);
  }
}

__global__ void k_dinv(float* __restrict__ deg, int n){
  int i = blockIdx.x*256 + threadIdx.x;
  if (i < n) deg[i] = 1.0f / sqrtf(deg[i] + 1.0f);
}

__global__ __launch_bounds__(1024)
void k_scan1(const int* __restrict__ cnt, int* __restrict__ rowptr,
             int* __restrict__ bsum, int n){
  __shared__ int wtot[16];
  int tid = threadIdx.x;
  int i = blockIdx.x*1024 + tid;
  int v = (i < n) ? cnt[i] : 0;
  #pragma unroll
  for (int off = 1; off < 64; off <<= 1){
    int t = __shfl_up(v, off, 64);
    if ((tid & 63) >= off) v += t;
  }
  int wid = tid >> 6;
  if ((tid & 63) == 63) wtot[wid] = v;
  __syncthreads();
  if (tid < 16){
    int t = wtot[tid];
    #pragma unroll
    for (int off = 1; off < 16; off <<= 1){
      int u = __shfl_up(t, off, 64);
      if (tid >= off) t += u;
    }
    wtot[tid] = t;
  }
  __syncthreads();
  int base = (wid > 0) ? wtot[wid-1] : 0;
  int incl = v + base;
  if (i < n) rowptr[i+1] = incl;
  if (tid == 1023) bsum[blockIdx.x] = incl;
}

__global__ void k_scan2(int* __restrict__ bsum, int nb){
  if (blockIdx.x == 0 && threadIdx.x == 0){
    int run = 0;
    for (int j = 0; j < nb; ++j){ int t = bsum[j]; bsum[j] = run; run += t; }
  }
}

__global__ void k_scan3(const int* __restrict__ cnt, int* __restrict__ rowptr,
                        int* __restrict__ cursor, const int* __restrict__ bsum, int n){
  int i = blockIdx.x*256 + threadIdx.x;
  if (i < n){
    int f = rowptr[i+1] + bsum[i >> 10];
    rowptr[i+1] = f;
    cursor[i] = f - cnt[i];
    if (i == 0) rowptr[0] = 0;
  }
}

__global__ void k_scatter(const int* __restrict__ ei, const float* __restrict__ ew,
                          const float* __restrict__ dinv, int* __restrict__ cursor,
                          int* __restrict__ csr_src, float* __restrict__ csr_w, int E){
  int e = blockIdx.x*256 + threadIdx.x;
  if (e < E){
    int s = ei[e], d = ei[E + e];
    int p = atomicAdd(&cursor[d], 1);
    csr_src[p] = s;
    csr_w[p] = dinv[s] * ew[e] * dinv[d];
  }
}

// Build W2^T padded+permuted hi/lo planes [NCOL2][KPAD]; also padded b2 / W3.
__global__ void k_convW2(const float* __restrict__ W2, const float* __restrict__ b2,
                         const float* __restrict__ W3,
                         __bf16* __restrict__ W2Th, __bf16* __restrict__ W2Tl,
                         float* __restrict__ b2p, float* __restrict__ W3p){
  int idx = blockIdx.x*256 + threadIdx.x;
  if (idx >= NCOL2*KPAD) return;
  int nn = idx / KPAD, kk = idx - nn*KPAD;
  int r = (kk < 12) ? kk : ((kk < 16) ? -1 : ((kk < 272) ? kk - 4 : -1));
  float v = (r >= 0 && nn < 268) ? W2[r*268 + nn] : 0.0f;
  __bf16 hb = (__bf16)v;
  long o = (long)nn*KPAD + kk;
  W2Th[o] = hb;
  W2Tl[o] = (__bf16)(v - (float)hb);
  if (kk == 0){
    b2p[nn] = (nn < 268) ? b2[nn] : 0.0f;
    W3p[nn] = (nn < 268) ? W3[nn] : 0.0f;
  }
}

// W1^T hi/lo planes [128][128].
__global__ void k_convW1(const float* __restrict__ W1,
                         __bf16* __restrict__ W1Th, __bf16* __restrict__ W1Tl){
  int idx = blockIdx.x*256 + threadIdx.x;
  if (idx >= HID*HID) return;
  int nn = idx >> 7, kk = idx & 127;
  float v = W1[kk*HID + nn];
  __bf16 hb = (__bf16)v;
  W1Th[idx] = hb;
  W1Tl[idx] = (__bf16)(v - (float)hb);
}

// Zero AT pad cols 272..287 (ws is re-poisoned each call).
__global__ void k_zerotail(__bf16* __restrict__ ATh, __bf16* __restrict__ ATl, int npad){
  int i = blockIdx.x*256 + threadIdx.x;
  if (i >= npad*16) return;
  int row = i >> 4, c = 272 + (i & 15);
  long o = (long)row*KPAD + c;
  ATh[o] = (__bf16)0.0f;
  ATl[o] = (__bf16)0.0f;
}

// ---------------- per-step kernels ----------------

// P = A@x -> AT cols 0..11 (hi/lo), cols 12..15 zeroed.  One node per wave. t=0 only.
__global__ __launch_bounds__(256)
void k_spmm12(const float* __restrict__ x, const int* __restrict__ rowptr,
              const int* __restrict__ csr_src, const float* __restrict__ csr_w,
              const float* __restrict__ dinv, __bf16* __restrict__ ATh,
              __bf16* __restrict__ ATl, int n){
  int lane = threadIdx.x & 63;
  int wid  = __builtin_amdgcn_readfirstlane(threadIdx.x >> 6);
  int node = blockIdx.x*4 + wid;
  if (node >= n) return;
  int f = lane & 15;
  int sub = lane >> 4;
  int k0 = rowptr[node], k1 = rowptr[node+1];
  float acc = 0.0f;
  if (sub == 0 && f < TP){
    float di = dinv[node];
    acc = di*di*x[node*TP + f];
  }
  for (int k = k0 + sub; k < k1; k += 4){
    float w = csr_w[k];
    int s = csr_src[k];
    if (f < TP) acc += w * x[s*TP + f];
  }
  acc += __shfl_xor(acc, 16, 64);
  acc += __shfl_xor(acc, 32, 64);
  if (sub == 0){
    long o = (long)node*KPAD + f;
    if (f < TP){
      __bf16 hb = (__bf16)acc;
      ATh[o] = hb;
      ATl[o] = (__bf16)(acc - (float)hb);
    } else {
      ATh[o] = (__bf16)0.0f;
      ATl[o] = (__bf16)0.0f;
    }
  }
}

// t>=1: P[:,0..10] = P[:,1..11] (in-row slide); P[:,11] = A@yp (1-col SpMV).
__global__ void k_shiftP(const float* __restrict__ yp, const int* __restrict__ rowptr,
                         const int* __restrict__ csr_src, const float* __restrict__ csr_w,
                         const float* __restrict__ dinv,
                         __bf16* __restrict__ ATh, __bf16* __restrict__ ATl, int n){
  int i = blockIdx.x*256 + threadIdx.x;
  if (i >= n) return;
  __bf16* rh = ATh + (long)i*KPAD;
  __bf16* rl = ATl + (long)i*KPAD;
  #pragma unroll
  for (int j = 0; j < TP-1; ++j){ rh[j] = rh[j+1]; rl[j] = rl[j+1]; }
  float di = dinv[i];
  float acc = di*di*yp[i];
  int k1 = rowptr[i+1];
  for (int k = rowptr[i]; k < k1; ++k) acc += csr_w[k]*yp[csr_src[k]];
  __bf16 hb = (__bf16)acc;
  rh[TP-1] = hb;
  rl[TP-1] = (__bf16)(acc - (float)hb);
}

// h0 = lrelu(P@W0 + b0); P reconstructed hi+lo from AT cols 0..11.
__global__ __launch_bounds__(256)
void k_mm0(const __bf16* __restrict__ ATh, const __bf16* __restrict__ ATl,
           const float* __restrict__ W0, const float* __restrict__ b0,
           float* __restrict__ h0, int n){
  __shared__ float Ws[TP*HID];
  for (int j = threadIdx.x; j < TP*HID; j += 256) Ws[j] = W0[j];
  __syncthreads();
  int f = threadIdx.x & 127;
  int half = threadIdx.x >> 7;
  float bf = b0[f];
  int base = blockIdx.x * 8;
  #pragma unroll
  for (int r = 0; r < 4; ++r){
    int node = base + half*4 + r;
    if (node < n){
      const __bf16* rh = ATh + (long)node*KPAD;
      const __bf16* rl = ATl + (long)node*KPAD;
      float acc = bf;
      #pragma unroll
      for (int k = 0; k < TP; ++k){
        float a = (float)rh[k] + (float)rl[k];
        acc += a * Ws[k*HID + f];
      }
      h0[(long)node*HID + f] = lrelu(acc);
    }
  }
}

// AT cols [colofs, colofs+128) = A@h (hi/lo bf16). One node per wave, float2/lane.
// Edge loop unrolled x2 with independent accumulators (more loads in flight).
__global__ __launch_bounds__(256)
void k_spmm128(const float* __restrict__ h, const int* __restrict__ rowptr,
               const int* __restrict__ csr_src, const float* __restrict__ csr_w,
               const float* __restrict__ dinv, __bf16* __restrict__ ATh,
               __bf16* __restrict__ ATl, int colofs, int n){
  int lane = threadIdx.x & 63;
  int wid  = __builtin_amdgcn_readfirstlane(threadIdx.x >> 6);
  int node = blockIdx.x*4 + wid;
  if (node >= n) return;
  int k0 = rowptr[node], k1 = rowptr[node+1];
  float di = dinv[node];
  float dd = di*di;
  float2 a0 = *(const float2*)(h + (long)node*HID + 2*lane);
  a0.x *= dd; a0.y *= dd;
  float2 a1 = {0.f, 0.f};
  int k = k0;
  for (; k + 2 <= k1; k += 2){
    float w0 = csr_w[k],   w1 = csr_w[k+1];
    int   s0 = csr_src[k], s1 = csr_src[k+1];
    float2 v0 = *(const float2*)(h + (long)s0*HID + 2*lane);
    float2 v1 = *(const float2*)(h + (long)s1*HID + 2*lane);
    a0.x += w0*v0.x; a0.y += w0*v0.y;
    a1.x += w1*v1.x; a1.y += w1*v1.y;
  }
  if (k < k1){
    float w0 = csr_w[k]; int s0 = csr_src[k];
    float2 v0 = *(const float2*)(h + (long)s0*HID + 2*lane);
    a0.x += w0*v0.x; a0.y += w0*v0.y;
  }
  float2 acc = {a0.x + a1.x, a0.y + a1.y};
  long o = (long)node*KPAD + colofs + 2*lane;
  __bf16 hx = (__bf16)acc.x, hy = (__bf16)acc.y;
  __bf16 lx = (__bf16)(acc.x - (float)hx), ly = (__bf16)(acc.y - (float)hy);
  *(unsigned int*)(ATh + o) = ((unsigned int)bfu(hy) << 16) | bfu(hx);
  *(unsigned int*)(ATl + o) = ((unsigned int)bfu(ly) << 16) | bfu(lx);
}

// MFMA split-bf16 matmul. A hi/lo planes [*, lda], B = W^T hi/lo planes [NT*16][ldb].
// Wave w owns rows block*64 + w*16 .. +15; A-frags preloaded once.
// Per nt-tile: ALL B-frags batched into register arrays (one latency window),
// then the 3*KS MFMA chain. NT loop fully unrolled so the scheduler can overlap
// next-tile loads with current-tile MFMAs.
// acc = Ahi*Bhi + Alo*Bhi + Ahi*Blo (fp32 MFMA accum; dropped lo*lo ~ 2^-18).
template<int KS, int NT, bool FUSE3>
__global__ __launch_bounds__(256, 2)
void k_mfma(const __bf16* __restrict__ Ah, const __bf16* __restrict__ Al, int lda,
            const __bf16* __restrict__ Bh, const __bf16* __restrict__ Bl, int ldb,
            const float* __restrict__ bias,
            float* __restrict__ C, int ldc,
            const float* __restrict__ W3, float* __restrict__ sout, int M){
  int lane = threadIdx.x & 63;
  int w    = threadIdx.x >> 6;
  int r16  = lane & 15;          // A-frag row / B-frag col / C col
  int kg   = lane >> 4;          // k-group 0..3
  long arow = (long)blockIdx.x*64 + w*16 + r16;
  const __bf16* pAh = Ah + arow*lda + kg*8;
  const __bf16* pAl = Al + arow*lda + kg*8;
  b8v ah[KS], al[KS];
  #pragma unroll
  for (int ks = 0; ks < KS; ++ks){
    ah[ks] = *(const b8v*)(pAh + ks*32);
    al[ks] = *(const b8v*)(pAl + ks*32);
  }
  float sacc[4] = {0.f, 0.f, 0.f, 0.f};
  #pragma unroll
  for (int nt = 0; nt < NT; ++nt){
    int col = nt*16 + r16;
    float bb  = bias[col];
    float w3v = FUSE3 ? W3[col] : 0.0f;
    const __bf16* pBh = Bh + (long)col*ldb + kg*8;
    const __bf16* pBl = Bl + (long)col*ldb + kg*8;
    b8v bh[KS], bl[KS];
    #pragma unroll
    for (int ks = 0; ks < KS; ++ks){
      bh[ks] = *(const b8v*)(pBh + ks*32);
      bl[ks] = *(const b8v*)(pBl + ks*32);
    }
    f4v acc = {0.f, 0.f, 0.f, 0.f};
    #pragma unroll
    for (int ks = 0; ks < KS; ++ks){
      acc = mfma16(ah[ks], bh[ks], acc);
      acc = mfma16(al[ks], bh[ks], acc);
      acc = mfma16(ah[ks], bl[ks], acc);
    }
    if constexpr (FUSE3){
      #pragma unroll
      for (int i = 0; i < 4; ++i) sacc[i] += lrelu(acc[i] + bb) * w3v;
    } else {
      #pragma unroll
      for (int i = 0; i < 4; ++i){
        long row = (long)blockIdx.x*64 + w*16 + kg*4 + i;   // C: col=lane&15, row=kg*4+i
        if (row < M) C[row*ldc + col] = lrelu(acc[i] + bb);
      }
    }
  }
  if constexpr (FUSE3){
    #pragma unroll
    for (int i = 0; i < 4; ++i){
      float v = sacc[i];
      v += __shfl_xor(v, 1, 64);
      v += __shfl_xor(v, 2, 64);
      v += __shfl_xor(v, 4, 64);
      v += __shfl_xor(v, 8, 64);
      sacc[i] = v;
    }
    if (r16 == 0){
      #pragma unroll
      for (int i = 0; i < 4; ++i){
        long row = (long)blockIdx.x*64 + w*16 + kg*4 + i;
        if (row < M) sout[row] = sacc[i];
      }
    }
  }
}

// yp = A@s + b3 ; out[:,t] = yp ; ypbuf = yp (feeds next step's k_shiftP).
__global__ void k_finalize(const float* __restrict__ s, const int* __restrict__ rowptr,
                           const int* __restrict__ csr_src, const float* __restrict__ csr_w,
                           const float* __restrict__ dinv, const float* __restrict__ b3,
                           float* __restrict__ ypbuf, float* __restrict__ out, int t, int n){
  int i = blockIdx.x*256 + threadIdx.x;
  if (i >= n) return;
  float di = dinv[i];
  float acc = di*di*s[i];
  int k1 = rowptr[i+1];
  for (int k = rowptr[i]; k < k1; ++k) acc += csr_w[k]*s[csr_src[k]];
  float yp = acc + b3[0];
  out[(long)i*TF + t] = yp;
  ypbuf[i] = yp;
}

// ---------------- launcher ----------------

extern "C" void kernel_launch(void* const* d_in, const int* in_sizes, int n_in,
                              void* d_out, int out_size, void* d_ws, size_t ws_size,
                              hipStream_t stream){
  const float* xin = (const float*)d_in[0];
  const int*   ei  = (const int*)  d_in[1];
  const float* ew  = (const float*)d_in[2];
  const float* W0  = (const float*)d_in[3];
  const float* b0  = (const float*)d_in[4];
  const float* W1  = (const float*)d_in[5];
  const float* b1  = (const float*)d_in[6];
  const float* W2  = (const float*)d_in[7];
  const float* b2  = (const float*)d_in[8];
  const float* W3  = (const float*)d_in[9];
  const float* b3  = (const float*)d_in[10];
  float* out = (float*)d_out;

  int n = in_sizes[0] / TP;
  int E = in_sizes[2];
  int npad = ((n + 63) / 64) * 64;

  char* p = (char*)d_ws;
  auto carve = [&](size_t bytes) -> void* {
    void* r = (void*)p;
    p += (bytes + 255) & ~(size_t)255;
    return r;
  };
  float*  dinv    = (float*) carve((size_t)n*4);
  int*    cnt     = (int*)   carve((size_t)n*4);
  int*    rowptr  = (int*)   carve((size_t)(n+1)*4);
  int*    cursor  = (int*)   carve((size_t)n*4);
  int*    bsum    = (int*)   carve(1024*4);
  int*    csr_src = (int*)   carve((size_t)E*4);
  float*  csr_w   = (float*) carve((size_t)E*4);
  float*  h       = (float*) carve((size_t)n*HID*4);      // h0 then h1
  __bf16* ATh     = (__bf16*)carve((size_t)npad*KPAD*2);
  __bf16* ATl     = (__bf16*)carve((size_t)npad*KPAD*2);
  __bf16* W2Th    = (__bf16*)carve((size_t)NCOL2*KPAD*2);
  __bf16* W2Tl    = (__bf16*)carve((size_t)NCOL2*KPAD*2);
  __bf16* W1Th    = (__bf16*)carve((size_t)HID*HID*2);
  __bf16* W1Tl    = (__bf16*)carve((size_t)HID*HID*2);
  float*  b2p     = (float*) carve(NCOL2*4);
  float*  W3p     = (float*) carve(NCOL2*4);
  float*  sbuf    = (float*) carve((size_t)n*4);
  float*  ypbuf   = (float*) carve((size_t)n*4);

  int gN  = (n + 255) / 256;
  int gE  = (E + 255) / 256;
  int nb  = (n + 1023) / 1024;
  int gW4 = (n + 3) / 4;
  int gM64 = (n + 63) / 64;

  k_init   <<<gN, 256, 0, stream>>>(dinv, cnt, n);
  k_degcnt <<<gE, 256, 0, stream>>>(ei, ew, dinv, cnt, E);
  k_dinv   <<<gN, 256, 0, stream>>>(dinv, n);
  k_scan1  <<<nb, 1024, 0, stream>>>(cnt, rowptr, bsum, n);
  k_scan2  <<<1, 64, 0, stream>>>(bsum, nb);
  k_scan3  <<<gN, 256, 0, stream>>>(cnt, rowptr, cursor, bsum, n);
  k_scatter<<<gE, 256, 0, stream>>>(ei, ew, dinv, cursor, csr_src, csr_w, E);
  k_convW2 <<<(NCOL2*KPAD + 255)/256, 256, 0, stream>>>(W2, b2, W3, W2Th, W2Tl, b2p, W3p);
  k_convW1 <<<(HID*HID + 255)/256, 256, 0, stream>>>(W1, W1Th, W1Tl);
  k_zerotail<<<(npad*16 + 255)/256, 256, 0, stream>>>(ATh, ATl, npad);

  for (int t = 0; t < TF; ++t){
    if (t == 0){
      k_spmm12<<<gW4, 256, 0, stream>>>(xin, rowptr, csr_src, csr_w, dinv, ATh, ATl, n);
    } else {
      k_shiftP<<<gN, 256, 0, stream>>>(ypbuf, rowptr, csr_src, csr_w, dinv, ATh, ATl, n);
    }
    k_mm0<<<(n + 7)/8, 256, 0, stream>>>(ATh, ATl, W0, b0, h, n);
    k_spmm128<<<gW4, 256, 0, stream>>>(h, rowptr, csr_src, csr_w, dinv, ATh, ATl, 16, n);
    // h1 = lrelu(Q@W1+b1): K=128 (4 ksteps), N=128 (8 ntiles)
    k_mfma<4, 8, false><<<gM64, 256, 0, stream>>>(ATh + 16, ATl + 16, KPAD,
                                                  W1Th, W1Tl, HID,
                                                  b1, h, HID, nullptr, nullptr, n);
    k_spmm128<<<gW4, 256, 0, stream>>>(h, rowptr, csr_src, csr_w, dinv, ATh, ATl, 144, n);
    // s = lrelu(AT@W2+b2)@W3: K=288 (9 ksteps), N=272 (17 ntiles), fused
    k_mfma<9, 17, true><<<gM64, 256, 0, stream>>>(ATh, ATl, KPAD,
                                                  W2Th, W2Tl, KPAD,
                                                  b2p, nullptr, 0, W3p, sbuf, n);
    k_finalize<<<gN, 256, 0, stream>>>(sbuf, rowptr, csr_src, csr_w, dinv, b3,
                                       ypbuf, out, t, n);
  }
}